// Round 2
// baseline (104.541 us; speedup 1.0000x reference)
//
#include <hip/hip_runtime.h>

// Problem constants (from reference): B=64, T=128, D=1024, H=512
#define B_ 64
#define T_ 128
#define D_ 1024
#define H_ 512

// Analytic simplification (verified R1, absmax 0.0 vs np ref):
//   logits[b,j,r] = hs[b,j] + xs[b,j+2+r] + fc_b ; lse - logits[...,0] cancels
//   hs and fc_b exactly, so the 2-step LSTM (W_ih/W_hh/b_*/w_h) is dead code.
//   loss(b,j) = LSE(xs[b, j+2..len_b-1]) - xs[b,j+2],  out = sum(loss)/sum(len-2)
//
// ws layout: xs[B*T] f32 | ploss[B] f32 | pcnt[B] i32 | ticket[1] i32

// ---------------------------------------------------------------------------
// Kernel A: xs[b,t] = dot(x[b,t,:], fc_w[H:]). One wave per row, 4x float4
// per lane, coalesced 16B/lane. Reads x (33.5 MB) exactly once -> ~6 us.
// Also zero-inits the ticket (ws is poisoned 0xAA before every timed call;
// stream order guarantees this lands before loss_kernel runs).
// ---------------------------------------------------------------------------
__global__ __launch_bounds__(256) void xs_kernel(const float* __restrict__ x,
                                                 const float* __restrict__ fc_w,
                                                 float* __restrict__ xs,
                                                 int* __restrict__ ticket) {
    if (blockIdx.x == 0 && threadIdx.x == 0) *ticket = 0;
    const float* wx = fc_w + H_;
    const int wave = threadIdx.x >> 6;
    const int lane = threadIdx.x & 63;
    const int row  = blockIdx.x * 4 + wave;          // row in [0, B*T)
    const float* base = x + (size_t)row * D_;
    float acc = 0.f;
#pragma unroll
    for (int k = 0; k < 4; ++k) {
        const int idx = k * 256 + lane * 4;          // 1KB/wave/iter, coalesced
        float4 v = *(const float4*)(base + idx);
        float4 w = *(const float4*)(wx + idx);
        acc += v.x * w.x + v.y * w.y + v.z * w.z + v.w * w.w;
    }
#pragma unroll
    for (int off = 32; off > 0; off >>= 1)
        acc += __shfl_down(acc, off, 64);
    if (lane == 0) xs[row] = acc;
}

// ---------------------------------------------------------------------------
// Kernel B (fused loss + final): one block per b, 128 threads. Thread j does
// the masked suffix-LSE from LDS. Per-block partials go out via agent-scope
// atomic stores; the last block (device-scope ticket) reduces the 64 partials
// with one wave and writes the scalar. Agent-scope atomics are the coherence
// point across non-coherent per-XCD L2s (G16).
// ---------------------------------------------------------------------------
__global__ __launch_bounds__(128) void loss_kernel(const int* __restrict__ mask,
                                                   const float* __restrict__ xs,
                                                   float* __restrict__ ploss,
                                                   int* __restrict__ pcnt,
                                                   int* __restrict__ ticket,
                                                   float* __restrict__ out) {
    __shared__ float sxs[T_];
    __shared__ int   sm[T_];
    __shared__ float sl[T_];
    __shared__ int   slast;
    const int b = blockIdx.x;
    const int t = threadIdx.x;
    sxs[t] = xs[b * T_ + t];
    sm[t]  = mask[b * T_ + t];
    __syncthreads();
    // len = sum(mask row), guaranteed >= 3
    for (int off = 64; off > 0; off >>= 1) {
        if (t < off) sm[t] += sm[t + off];
        __syncthreads();
    }
    const int len = sm[0];

    float loss = 0.f;
    if (t <= len - 3) {
        const int p0 = t + 2;
        float m = sxs[p0];
        for (int p = p0 + 1; p < len; ++p) m = fmaxf(m, sxs[p]);
        float s = 0.f;
        for (int p = p0; p < len; ++p) s += __expf(sxs[p] - m);
        loss = m + __logf(s) - sxs[p0];
    }
    sl[t] = loss;
    __syncthreads();
    for (int off = 64; off > 0; off >>= 1) {
        if (t < off) sl[t] += sl[t + off];
        __syncthreads();
    }
    if (t == 0) {
        __hip_atomic_store(&ploss[b], sl[0], __ATOMIC_RELAXED, __HIP_MEMORY_SCOPE_AGENT);
        __hip_atomic_store(&pcnt[b], len - 2, __ATOMIC_RELAXED, __HIP_MEMORY_SCOPE_AGENT);
        int old = __hip_atomic_fetch_add(ticket, 1, __ATOMIC_ACQ_REL, __HIP_MEMORY_SCOPE_AGENT);
        slast = (old == B_ - 1) ? 1 : 0;
    }
    __syncthreads();
    if (slast && t < 64) {
        float l = __hip_atomic_load(&ploss[t], __ATOMIC_RELAXED, __HIP_MEMORY_SCOPE_AGENT);
        float c = (float)__hip_atomic_load(&pcnt[t], __ATOMIC_RELAXED, __HIP_MEMORY_SCOPE_AGENT);
#pragma unroll
        for (int off = 32; off > 0; off >>= 1) {
            l += __shfl_down(l, off, 64);
            c += __shfl_down(c, off, 64);
        }
        if (t == 0) out[0] = l / c;
    }
}

extern "C" void kernel_launch(void* const* d_in, const int* in_sizes, int n_in,
                              void* d_out, int out_size, void* d_ws, size_t ws_size,
                              hipStream_t stream) {
    // setup_inputs order: encoder_output, mask, W_ih, W_hh, b_ih, b_hh, fc_w, fc_b
    const float* x    = (const float*)d_in[0];
    const int*   mask = (const int*)d_in[1];
    const float* fc_w = (const float*)d_in[6];
    float* out = (float*)d_out;

    float* xs     = (float*)d_ws;           // B*T floats
    float* ploss  = xs + B_ * T_;           // B floats
    int*   pcnt   = (int*)(ploss + B_);     // B ints
    int*   ticket = pcnt + B_;              // 1 int

    xs_kernel<<<(B_ * T_) / 4, 256, 0, stream>>>(x, fc_w, xs, ticket);
    loss_kernel<<<B_, 128, 0, stream>>>(mask, xs, ploss, pcnt, ticket, out);
}